// Round 5
// baseline (81.757 us; speedup 1.0000x reference)
//
#include <hip/hip_runtime.h>

// mrnLoss: out = sum((w_preds - w_stars)^2) + N - sum_n( y_n * <feats_n, w_preds[seg_n]> )
// C=1000, D=512, N=200000. Memory-bound: ~416 MB total read -> ~63us floor @6.6TB/s.
//
// R5 changes vs R4 (78.7us):
//  - drop the final_reduce kernel node: hipMemsetAsync(d_out,0,4) memset node
//    + per-block atomicAdd; block 0 folds in the +N constant. One kernel node
//    + one cheap memset node instead of two kernel nodes.
//  - wst loads non-temporal in part 1 (read-once; don't evict wp from L2 --
//    part 2's gather depends on wp staying L2-resident)
//  - loop body unchanged from R4 (readlane-broadcast, NT feats, unroll 3)

#define BLOCK 256
#define GRID  1024
#define CHUNK 49
#define NWAVES (GRID * (BLOCK / 64))   // 4096 waves

typedef float vf4 __attribute__((ext_vector_type(4)));

__device__ __forceinline__ float dot8(vf4 a0, vf4 a1, vf4 u0, vf4 u1) {
    return a0.x * u0.x + a0.y * u0.y + a0.z * u0.z + a0.w * u0.w
         + a1.x * u1.x + a1.y * u1.y + a1.z * u1.z + a1.w * u1.w;
}

__global__ __launch_bounds__(BLOCK, 4) void mrn_loss_kernel(
    const float* __restrict__ wp,   // (C, D) = (1000, 512)
    const float* __restrict__ wst,  // (C, D)
    const float* __restrict__ feats,// (N, D)
    const float* __restrict__ ys,   // (N,)
    const int*   __restrict__ seg,  // (N,)
    float* __restrict__ out,        // pre-zeroed by memset node
    int N)
{
    const int tid      = blockIdx.x * BLOCK + threadIdx.x;
    const int nthreads = GRID * BLOCK;

    float acc_a = 0.0f;
    float acc_b = 0.0f;

    // ---- Part 1: reg_loss = sum((wp - wst)^2); warms wp into every XCD L2.
    // wst is read-once -> non-temporal so it doesn't evict wp.
    {
        const int REG4 = (1000 * 512) / 4;
        const vf4* wp4 = (const vf4*)wp;
        const vf4* ws4 = (const vf4*)wst;
        for (int i = tid; i < REG4; i += nthreads) {
            vf4 a = wp4[i];
            vf4 b = __builtin_nontemporal_load(ws4 + i);
            vf4 d = a - b;
            acc_a += d.x * d.x + d.y * d.y + d.z * d.z + d.w * d.w;
        }
    }

    // ---- Part 2: -sum_n y_n * <feats_n, wp[seg_n]>
    // One wave per CHUNK=49 consecutive samples (98KB contiguous feats stream).
    {
        const int lane = threadIdx.x & 63;
        const int wave = __builtin_amdgcn_readfirstlane(tid >> 6);

        for (int base = wave * CHUNK; base < N; base += NWAVES * CHUNK) {
            const int cnt = min(CHUNK, N - base);

            // Coalesced preload of this chunk's seg/ys (one transaction each).
            int   myseg = 0;
            float myy   = 0.0f;
            if (lane < cnt) {
                myseg = seg[base + lane];
                myy   = ys[base + lane];
            }

            const vf4* f4 = (const vf4*)feats + (size_t)base * 128;

            if (cnt == CHUNK) {
                #pragma unroll 3
                for (int j = 0; j < CHUNK; ++j) {
                    const int   c = __builtin_amdgcn_readlane(myseg, j);
                    const float y = __int_as_float(
                        __builtin_amdgcn_readlane(__float_as_int(myy), j));

                    const vf4* fr = f4 + (size_t)j * 128;
                    const vf4* wr = (const vf4*)(wp + (size_t)c * 512);

                    vf4 a0 = __builtin_nontemporal_load(fr + lane);
                    vf4 a1 = __builtin_nontemporal_load(fr + lane + 64);
                    vf4 u0 = wr[lane];
                    vf4 u1 = wr[lane + 64];

                    const float d = dot8(a0, a1, u0, u1);
                    if (j & 1) acc_b -= y * d;
                    else       acc_a -= y * d;
                }
            } else {
                for (int j = 0; j < cnt; ++j) {
                    const int   c = __builtin_amdgcn_readlane(myseg, j);
                    const float y = __int_as_float(
                        __builtin_amdgcn_readlane(__float_as_int(myy), j));
                    const vf4* fr = f4 + (size_t)j * 128;
                    const vf4* wr = (const vf4*)(wp + (size_t)c * 512);
                    vf4 a0 = __builtin_nontemporal_load(fr + lane);
                    vf4 a1 = __builtin_nontemporal_load(fr + lane + 64);
                    vf4 u0 = wr[lane];
                    vf4 u1 = wr[lane + 64];
                    acc_a -= y * dot8(a0, a1, u0, u1);
                }
            }
        }
    }

    // ---- Reduce: shuffle within wave, LDS across waves, one atomic per block.
    float acc = acc_a + acc_b;
    for (int off = 32; off > 0; off >>= 1)
        acc += __shfl_down(acc, off, 64);

    __shared__ float sacc[BLOCK / 64];
    const int lane = threadIdx.x & 63;
    const int wid  = threadIdx.x >> 6;
    if (lane == 0) sacc[wid] = acc;
    __syncthreads();

    if (threadIdx.x == 0) {
        float b = sacc[0] + sacc[1] + sacc[2] + sacc[3];
        if (blockIdx.x == 0) b += (float)N;   // fold the +1-per-sample constant
        atomicAdd(out, b);
    }
}

extern "C" void kernel_launch(void* const* d_in, const int* in_sizes, int n_in,
                              void* d_out, int out_size, void* d_ws, size_t ws_size,
                              hipStream_t stream) {
    const float* wp    = (const float*)d_in[0];
    const float* wst   = (const float*)d_in[1];
    const float* feats = (const float*)d_in[2];
    const float* ys    = (const float*)d_in[3];
    const int*   seg   = (const int*)d_in[4];
    float* out = (float*)d_out;

    const int N = in_sizes[3];   // 200000 samples

    // Cheap memset node (not a kernel dispatch): out = 0.0f
    hipMemsetAsync(out, 0, sizeof(float), stream);
    mrn_loss_kernel<<<GRID, BLOCK, 0, stream>>>(wp, wst, feats, ys, seg, out, N);
}